// Round 3
// baseline (289.535 us; speedup 1.0000x reference)
//
#include <hip/hip_runtime.h>
#include <hip/hip_bf16.h>
#include <hip/hip_fp16.h>
#include <math.h>

#define EPS 1e-3f
// B=4, S=256, D=256, v=128, e=64, c=192, NH=8, DK=8, DV=8

// ws layout (floats):
// 8192   : cK[64], 8256: dK[64], 8320: cV[64], 8384: dV[64]
// 8448   : q_s [B*D*64]  (relu(q)/sqrt(8))
// 73984  : Pd  [B*D*64]  (V_dst @ We[128:256])
// 139520 : sv  [B*S]     (sum of V_src row)
// 140544 : ssv [B*S]     (sumsq of V_src row)
// 141568 : Qs_k[B*S*64]  (g_in-folded V_src @ Wk[0:128])
// 207104 : Qs_v[B*S*64]
// 272640 : Ps  [B*S*64]  (V_src @ We[0:128])
// 338176 : Wcat bf16 [192 n][64 k]  = [g_in*WkE | g_in*WvE | We3]  (12288 ushort)
#define WCAT_OFF 338176

typedef __attribute__((ext_vector_type(8))) short short8;
typedef __attribute__((ext_vector_type(8))) unsigned short ushort8;
typedef __attribute__((ext_vector_type(4))) float floatx4;

__device__ __forceinline__ unsigned short f2bf(float f) {
    __hip_bfloat16 h = __float2bfloat16(f);
    return *reinterpret_cast<unsigned short*>(&h);
}

// One kernel, five block roles:
//  bid < 1024           : dst path (per (b,d)): LN(V_dst)->q; Pd
//  bid < 2048           : src path (per (b,s)): stats; Qs_k; Qs_v; Ps
//  bid == 2048          : cK/dK/cV/dV
//  bid in [2049, 2057)  : Wcat bf16 fill (24 n-rows per block)
//  bid in [2057, 2121)  : out2 = 1.0f fill (4096 floats per block)
__global__ __launch_bounds__(256) void pre_kernel(
        const float* __restrict__ V_src, const float* __restrict__ V_dst,
        const float* __restrict__ g_vd, const float* __restrict__ b_vd,
        const float* __restrict__ g_in, const float* __restrict__ b_in,
        const float* __restrict__ Wq, const float* __restrict__ bq,
        const float* __restrict__ Wk, const float* __restrict__ bk,
        const float* __restrict__ Wv, const float* __restrict__ bv,
        const float* __restrict__ We,
        float* __restrict__ ws, float* __restrict__ out2) {
    int bid = blockIdx.x, tid = threadIdx.x;
    __shared__ float row[128], vn[128], rs1[2], rs2[2];

    if (bid < 1024) {                       // ---- dst path ----
        int blk = bid;
        if (tid < 128) {
            float x = V_dst[blk * 128 + tid];
            row[tid] = x;
            float s1 = x, s2 = x * x;
            #pragma unroll
            for (int o = 1; o <= 32; o <<= 1) { s1 += __shfl_xor(s1, o); s2 += __shfl_xor(s2, o); }
            int w = tid >> 6, l = tid & 63;
            if (l == 0) { rs1[w] = s1; rs2[w] = s2; }
        }
        __syncthreads();
        if (tid < 128) {
            float sum = rs1[0] + rs1[1], ssq = rs2[0] + rs2[1];
            float mu = sum * (1.f / 128.f);
            float var = ssq * (1.f / 128.f) - mu * mu;
            float rsig = rsqrtf(var + EPS);
            vn[tid] = (row[tid] - mu) * rsig * g_vd[tid] + b_vd[tid];
        }
        __syncthreads();
        int n = tid & 63;
        if (tid < 64) {
            float acc = bq[n];
            for (int j = 0; j < 128; j++) acc += vn[j] * Wq[j * 64 + n];
            ws[8448 + blk * 64 + n] = fmaxf(acc, 0.f) * 0.35355339059327373f;
        } else if (tid < 128) {
            float acc = 0.f;
            for (int j = 0; j < 128; j++) acc += row[j] * We[(128 + j) * 64 + n];
            ws[73984 + blk * 64 + n] = acc;
        }
    } else if (bid < 2048) {                // ---- src path ----
        int blk = bid - 1024;
        if (tid < 128) row[tid] = V_src[blk * 128 + tid];
        __syncthreads();
        if (tid < 64) {
            float a = row[tid], b2 = row[tid + 64];
            float s1 = a + b2, s2 = a * a + b2 * b2;
            #pragma unroll
            for (int o = 1; o <= 32; o <<= 1) { s1 += __shfl_xor(s1, o); s2 += __shfl_xor(s2, o); }
            if (tid == 0) { ws[139520 + blk] = s1; ws[140544 + blk] = s2; }
        }
        int g = tid >> 6, n = tid & 63;
        if (g == 0) {
            float acc = 0.f;
            for (int j = 0; j < 128; j++) acc += row[j] * g_in[j] * Wk[j * 64 + n];
            ws[141568 + blk * 64 + n] = acc;
        } else if (g == 1) {
            float acc = 0.f;
            for (int j = 0; j < 128; j++) acc += row[j] * g_in[j] * Wv[j * 64 + n];
            ws[207104 + blk * 64 + n] = acc;
        } else if (g == 2) {
            float acc = 0.f;
            for (int j = 0; j < 128; j++) acc += row[j] * We[j * 64 + n];
            ws[272640 + blk * 64 + n] = acc;
        }
    } else if (bid == 2048) {               // ---- cK/dK/cV/dV ----
        int n = tid & 63;
        if (tid < 64) {
            float c = 0.f, dd = 0.f;
            for (int j = 0; j < 192; j++) { float w = Wk[j * 64 + n]; c += g_in[j] * w; dd += b_in[j] * w; }
            ws[8192 + n] = c; ws[8256 + n] = dd + bk[n];
        } else if (tid < 128) {
            float c = 0.f, dd = 0.f;
            for (int j = 0; j < 192; j++) { float w = Wv[j * 64 + n]; c += g_in[j] * w; dd += b_in[j] * w; }
            ws[8320 + n] = c; ws[8384 + n] = dd + bv[n];
        }
    } else if (bid < 2057) {                // ---- Wcat fill (24 rows/block) ----
        unsigned short* wcat = (unsigned short*)(ws + WCAT_OFF);
        int base = (bid - 2049) * 1536;
        for (int ii = tid; ii < 1536; ii += 256) {
            int idx = base + ii;
            int nn = idx >> 6, k = idx & 63;
            float w;
            if (nn < 64)       w = g_in[128 + k] * Wk[(128 + k) * 64 + nn];
            else if (nn < 128) w = g_in[128 + k] * Wv[(128 + k) * 64 + (nn - 64)];
            else               w = We[(256 + k) * 64 + (nn - 128)];
            wcat[idx] = f2bf(w);
        }
    } else {                                // ---- out2 = 1 ----
        float* p = out2 + (bid - 2057) * 4096;
        float4 one = make_float4(1.f, 1.f, 1.f, 1.f);
        #pragma unroll
        for (int i = 0; i < 4; i++) *(float4*)(p + (i * 256 + tid) * 4) = one;
    }
}

// Fused per (b,d) block: stage E bf16 -> MFMA (qek|qev|pe via L1-hot Wcat) ->
// fp16 res in LDS -> per-row softmax-over-heads epilogue + E_new + attn out.
// All main-loop LDS traffic is wave-local: single __syncthreads at the end.
__global__ __launch_bounds__(256, 4) void fused_kernel(
        const float* __restrict__ E, const float* __restrict__ A,
        const float* __restrict__ V_dst,
        const float* __restrict__ Wo, const float* __restrict__ bo,
        const float* __restrict__ be,
        const float* __restrict__ ws,
        float* __restrict__ out0, float* __restrict__ out1) {
    int blk = blockIdx.x;
    int b = blk >> 8, d = blk & 255;
    int tid = threadIdx.x, wv = tid >> 6, lane = tid & 63;
    int col = lane & 15, quad = lane >> 4;

    __shared__ unsigned short Ebf[64 * 72];   // 64 rows x 64 bf16, stride 72 (pad)
    __shared__ __half res[64 * 196];          // 64 rows x 192 fp16, stride 196 (pad)
    __shared__ float ssum[64], sssq[64];
    __shared__ float osm[4][64];
    __shared__ float otot[64];

    float cK = ws[8192 + lane], dK = ws[8256 + lane];
    float cV = ws[8320 + lane], dV = ws[8384 + lane];
    float qs  = ws[8448 + blk * 64 + lane];
    float pdv = ws[73984 + blk * 64 + lane];
    float beL = be[lane];
    const float* sv  = ws + 139520 + b * 256;
    const float* ssv = ws + 140544 + b * 256;
    const float* Qsk = ws + 141568 + (size_t)b * 16384;
    const float* Qsv = ws + 207104 + (size_t)b * 16384;
    const float* Ps  = ws + 272640 + (size_t)b * 16384;
    const unsigned short* Wcat = (const unsigned short*)(ws + WCAT_OFF);

    float o_acc = 0.f;
    int rstage = tid >> 2, gstage = tid & 3;   // staging: 4 threads per row

    for (int chunk = 0; chunk < 4; chunk++) {
        int s0 = chunk * 64;
        // ---- stage 64 rows of E (fp32 -> bf16) + exact fp32 row stats ----
        {
            const float* ep = E + ((size_t)(((b * 256 + s0 + rstage) * 256 + d))) * 64 + gstage * 16;
            float4 e0 = *(const float4*)(ep);
            float4 e1 = *(const float4*)(ep + 4);
            float4 e2 = *(const float4*)(ep + 8);
            float4 e3 = *(const float4*)(ep + 12);
            float s1 = (e0.x + e0.y + e0.z + e0.w) + (e1.x + e1.y + e1.z + e1.w)
                     + (e2.x + e2.y + e2.z + e2.w) + (e3.x + e3.y + e3.z + e3.w);
            float s2 = (e0.x*e0.x + e0.y*e0.y + e0.z*e0.z + e0.w*e0.w)
                     + (e1.x*e1.x + e1.y*e1.y + e1.z*e1.z + e1.w*e1.w)
                     + (e2.x*e2.x + e2.y*e2.y + e2.z*e2.z + e2.w*e2.w)
                     + (e3.x*e3.x + e3.y*e3.y + e3.z*e3.z + e3.w*e3.w);
            s1 += __shfl_xor(s1, 1); s2 += __shfl_xor(s2, 1);
            s1 += __shfl_xor(s1, 2); s2 += __shfl_xor(s2, 2);
            if (gstage == 0) { ssum[rstage] = s1; sssq[rstage] = s2; }
            ushort8 w0, w1;
            w0[0]=f2bf(e0.x); w0[1]=f2bf(e0.y); w0[2]=f2bf(e0.z); w0[3]=f2bf(e0.w);
            w0[4]=f2bf(e1.x); w0[5]=f2bf(e1.y); w0[6]=f2bf(e1.z); w0[7]=f2bf(e1.w);
            w1[0]=f2bf(e2.x); w1[1]=f2bf(e2.y); w1[2]=f2bf(e2.z); w1[3]=f2bf(e2.w);
            w1[4]=f2bf(e3.x); w1[5]=f2bf(e3.y); w1[6]=f2bf(e3.z); w1[7]=f2bf(e3.w);
            *(ushort8*)(Ebf + rstage * 72 + gstage * 16)     = w0;
            *(ushort8*)(Ebf + rstage * 72 + gstage * 16 + 8) = w1;
        }
        // ---- MFMA: wave wv computes its 16 rows x 192 cols (wave-local) ----
        // B-fragments streamed from global Wcat (48 KB, L1-resident).
        {
            short8 a0 = *(const short8*)(Ebf + (wv * 16 + col) * 72 + quad * 8);
            short8 a1 = *(const short8*)(Ebf + (wv * 16 + col) * 72 + 32 + quad * 8);
            #pragma unroll
            for (int t = 0; t < 12; t++) {
                short8 b0 = *(const short8*)(Wcat + ((t * 16 + col) * 64 + quad * 8));
                short8 b1 = *(const short8*)(Wcat + ((t * 16 + col) * 64 + 32 + quad * 8));
                floatx4 acc = {0.f, 0.f, 0.f, 0.f};
                acc = __builtin_amdgcn_mfma_f32_16x16x32_bf16(a0, b0, acc, 0, 0, 0);
                acc = __builtin_amdgcn_mfma_f32_16x16x32_bf16(a1, b1, acc, 0, 0, 0);
                #pragma unroll
                for (int r = 0; r < 4; r++)
                    res[(wv * 16 + quad * 4 + r) * 196 + t * 16 + col] = __float2half(acc[r]);
            }
        }
        // ---- per-row epilogue: softmax over heads + E_new (wave-local) ----
        #pragma unroll 4
        for (int i = 0; i < 16; i++) {
            int sl = wv * 16 + i;
            int s = s0 + sl;
            int row = (b * 256 + s) * 256 + d;
            float a = A[row];
            float qek = __half2float(res[sl * 196 + lane]);
            float qev = __half2float(res[sl * 196 + 64 + lane]);
            float pe  = __half2float(res[sl * 196 + 128 + lane]);
            float mu  = (a * sv[s] + ssum[sl]) * (1.f / 192.f);
            float ex2 = (a * a * ssv[s] + sssq[sl]) * (1.f / 192.f);
            float rsig = rsqrtf(ex2 - mu * mu + EPS);
            float kk = fmaxf(rsig * (a * Qsk[s * 64 + lane] + qek) - rsig * mu * cK + dK, 0.f);
            float vl = fmaxf(rsig * (a * Qsv[s * 64 + lane] + qev) - rsig * mu * cV + dV, 0.f);
            float sc = qs * kk;                       // q pre-scaled by 1/sqrt(8)
            sc += __shfl_xor(sc, 1); sc += __shfl_xor(sc, 2); sc += __shfl_xor(sc, 4);
            // softmax over heads, shift-free (scores bounded far below exp overflow)
            float p = __expf(sc);
            float den = p;
            den += __shfl_xor(den, 8); den += __shfl_xor(den, 16); den += __shfl_xor(den, 32);
            o_acc += p * __builtin_amdgcn_rcpf(den) * vl;
            out1[(size_t)row * 64 + lane] = fmaxf(a * (Ps[s * 64 + lane] + pdv) + pe + beL, 0.f);
        }
    }
    // ---- cross-wave o reduction + Wo epilogue ----
    osm[wv][lane] = o_acc;
    __syncthreads();
    if (tid < 64) otot[tid] = osm[0][tid] + osm[1][tid] + osm[2][tid] + osm[3][tid];
    __syncthreads();
    if (tid < 128) {
        float acc = bo[tid];
        for (int n = 0; n < 64; n++) acc += otot[n] * Wo[n * 128 + tid];
        out0[blk * 128 + tid] = V_dst[blk * 128 + tid] + fmaxf(acc, 0.f);
    }
}

extern "C" void kernel_launch(void* const* d_in, const int* in_sizes, int n_in,
                              void* d_out, int out_size, void* d_ws, size_t ws_size,
                              hipStream_t stream) {
    (void)in_sizes; (void)n_in; (void)out_size; (void)ws_size;
    const float* V_src = (const float*)d_in[0];
    const float* V_dst = (const float*)d_in[1];
    const float* E     = (const float*)d_in[2];
    const float* A     = (const float*)d_in[3];
    const float* g_vd  = (const float*)d_in[4];
    const float* b_vd  = (const float*)d_in[5];
    const float* g_in  = (const float*)d_in[6];
    const float* b_in  = (const float*)d_in[7];
    const float* Wq    = (const float*)d_in[8];
    const float* bq    = (const float*)d_in[9];
    const float* Wk    = (const float*)d_in[10];
    const float* bk    = (const float*)d_in[11];
    const float* Wv    = (const float*)d_in[12];
    const float* bv    = (const float*)d_in[13];
    const float* Wo    = (const float*)d_in[14];
    const float* bo    = (const float*)d_in[15];
    const float* We    = (const float*)d_in[16];
    const float* be    = (const float*)d_in[17];
    float* ws   = (float*)d_ws;
    float* out0 = (float*)d_out;
    float* out1 = out0 + 131072;            // E_new [B,S,D,64]
    float* out2 = out1 + 16777216;          // A_new [B,S,D]

    hipLaunchKernelGGL(pre_kernel,   dim3(2121), dim3(256), 0, stream,
                       V_src, V_dst, g_vd, b_vd, g_in, b_in, Wq, bq, Wk, bk, Wv, bv, We, ws, out2);
    hipLaunchKernelGGL(fused_kernel, dim3(1024), dim3(256), 0, stream,
                       E, A, V_dst, Wo, bo, be, ws, out0, out1);
}